// Round 1
// baseline (97.371 us; speedup 1.0000x reference)
//
#include <hip/hip_runtime.h>
#include <hip/hip_bf16.h>
#include <stdint.h>

typedef __attribute__((ext_vector_type(4))) float  f32x4;
typedef __attribute__((ext_vector_type(8))) __bf16 bf16x8;

constexpr int F_DIM = 128;   // feature dim
constexpr int KC    = 256;   // number of centers
// u = max(sq, 1e-24)^(-1/(M-1)),  M = 1.7  ->  exponent on sq is -1/0.7
constexpr float ALPHA = -1.4285714285714286f;

__device__ __forceinline__ unsigned short f2bf(float f) {
    union { float f; unsigned int u; } v; v.f = f;
    unsigned int u = v.u;
    // round-to-nearest-even bf16
    unsigned int r = (u + 0x7fffu + ((u >> 16) & 1u)) >> 16;
    return (unsigned short)r;
}

__global__ __launch_bounds__(512, 2) void fcm_kernel(
        const float* __restrict__ x,
        const float* __restrict__ centers,
        float* __restrict__ out)
{
    // swizzled bf16 centers: row j, 16B chunk kc at byte j*256 + ((kc*16) ^ ((j&7)<<4))
    __shared__ __align__(16) unsigned char sB[KC * F_DIM * 2]; // 64 KiB
    __shared__ float sC2[KC];
    __shared__ float sC2p[512];

    const int tid  = threadIdx.x;
    const int lane = tid & 63;
    const int wave = tid >> 6;

    // ---------- stage centers -> LDS (bf16, swizzled) + c2 (fp32 exact) ----------
    {
        const int j = tid >> 1;      // center index 0..255
        const int h = tid & 1;       // which half of the 128 features
        const float* src = centers + j * F_DIM + h * 64;
        float ss = 0.f;
        #pragma unroll
        for (int c = 0; c < 8; ++c) {
            f32x4 a = *(const f32x4*)(src + c * 8);
            f32x4 b = *(const f32x4*)(src + c * 8 + 4);
            ss += a.x*a.x + a.y*a.y + a.z*a.z + a.w*a.w;
            ss += b.x*b.x + b.y*b.y + b.z*b.z + b.w*b.w;
            union { unsigned short us[8]; uint4 v; } pk;
            pk.us[0] = f2bf(a.x); pk.us[1] = f2bf(a.y);
            pk.us[2] = f2bf(a.z); pk.us[3] = f2bf(a.w);
            pk.us[4] = f2bf(b.x); pk.us[5] = f2bf(b.y);
            pk.us[6] = f2bf(b.z); pk.us[7] = f2bf(b.w);
            const int kchunk = h * 8 + c;                       // 0..15
            const int off = j * 256 + ((kchunk * 16) ^ ((j & 7) << 4));
            *(uint4*)(sB + off) = pk.v;
        }
        sC2p[tid] = ss;
    }
    __syncthreads();
    if (tid < KC) sC2[tid] = sC2p[2 * tid] + sC2p[2 * tid + 1];
    __syncthreads();

    // ---------- load A fragments (16 rows per wave) + exact fp32 x2 ----------
    const int rbase = blockIdx.x * 128 + wave * 16;
    const int lrow  = lane & 15;   // row within 16-row tile / col within 16-col tile
    const int kq    = lane >> 4;   // k-quarter 0..3
    const float* xrow = x + (long long)(rbase + lrow) * F_DIM + kq * 8;

    bf16x8 fragA[4];
    float x2 = 0.f;
    #pragma unroll
    for (int kb = 0; kb < 4; ++kb) {
        f32x4 a = *(const f32x4*)(xrow + kb * 32);
        f32x4 b = *(const f32x4*)(xrow + kb * 32 + 4);
        x2 += a.x*a.x + a.y*a.y + a.z*a.z + a.w*a.w;
        x2 += b.x*b.x + b.y*b.y + b.z*b.z + b.w*b.w;
        union { unsigned short us[8]; bf16x8 v; } pk;
        pk.us[0] = f2bf(a.x); pk.us[1] = f2bf(a.y);
        pk.us[2] = f2bf(a.z); pk.us[3] = f2bf(a.w);
        pk.us[4] = f2bf(b.x); pk.us[5] = f2bf(b.y);
        pk.us[6] = f2bf(b.z); pk.us[7] = f2bf(b.w);
        fragA[kb] = pk.v;
    }
    // lanes {l, l^16, l^32, l^48} hold disjoint quarters of row (lane&15)
    x2 += __shfl_xor(x2, 16);
    x2 += __shfl_xor(x2, 32);
    // now every lane holds ||x_row||^2 for row rbase + (lane&15)

    // ---------- MFMA: C[i][j] = x_i . c_j over all 256 centers ----------
    f32x4 acc[16];
    #pragma unroll
    for (int nt = 0; nt < 16; ++nt) acc[nt] = f32x4{0.f, 0.f, 0.f, 0.f};

    #pragma unroll
    for (int nt = 0; nt < 16; ++nt) {
        const int j = nt * 16 + lrow;
        const unsigned char* brow = sB + j * 256;
        const int sw = (j & 7) << 4;
        #pragma unroll
        for (int kb = 0; kb < 4; ++kb) {
            bf16x8 fb = *(const bf16x8*)(brow + ((kb * 64 + kq * 16) ^ sw));
            acc[nt] = __builtin_amdgcn_mfma_f32_16x16x32_bf16(fragA[kb], fb, acc[nt], 0, 0, 0);
        }
    }

    // ---------- epilogue: sq -> u = sq^ALPHA, row-normalize, store ----------
    // C/D layout: col = lane&15, row = (lane>>4)*4 + reg   [m89/m91 verified]
    float x2r[4], rowsum[4];
    #pragma unroll
    for (int r = 0; r < 4; ++r) {
        x2r[r] = __shfl(x2, kq * 4 + r);   // x2 of output row (kq*4 + r)
        rowsum[r] = 0.f;
    }

    #pragma unroll
    for (int nt = 0; nt < 16; ++nt) {
        const float c2v = sC2[nt * 16 + lrow];
        #pragma unroll
        for (int r = 0; r < 4; ++r) {
            float sq = fmaxf(x2r[r] + c2v - 2.0f * acc[nt][r], 1e-24f);
            float u  = __builtin_amdgcn_exp2f(ALPHA * __builtin_amdgcn_logf(sq));
            acc[nt][r] = u;
            rowsum[r] += u;
        }
    }

    #pragma unroll
    for (int r = 0; r < 4; ++r) {
        float s = rowsum[r];
        s += __shfl_xor(s, 1);
        s += __shfl_xor(s, 2);
        s += __shfl_xor(s, 4);
        s += __shfl_xor(s, 8);
        rowsum[r] = __builtin_amdgcn_rcpf(s);
    }

    float* orow = out + ((long long)rbase + kq * 4) * KC + lrow;
    #pragma unroll
    for (int r = 0; r < 4; ++r) {
        #pragma unroll
        for (int nt = 0; nt < 16; ++nt) {
            orow[(long long)r * KC + nt * 16] = acc[nt][r] * rowsum[r];
        }
    }
}

extern "C" void kernel_launch(void* const* d_in, const int* in_sizes, int n_in,
                              void* d_out, int out_size, void* d_ws, size_t ws_size,
                              hipStream_t stream) {
    const float* x       = (const float*)d_in[0];
    const float* centers = (const float*)d_in[1];
    float* out           = (float*)d_out;

    const int N      = in_sizes[0] / F_DIM;   // 262144
    const int blocks = N / 128;               // 128 rows per block
    fcm_kernel<<<blocks, 512, 0, stream>>>(x, centers, out);
}